// Round 9
// baseline (574.203 us; speedup 1.0000x reference)
//
#include <hip/hip_runtime.h>
#include <math.h>

#define N_NODES 100000
#define N_EDGES 3200000
#define IN_CH 32
#define HID 64
#define BW 512                               // dst nodes per bucket
#define NB ((N_NODES + BW - 1) / BW)         // 196 buckets
#define CAP 17408                            // fixed capacity (mean 16384 + >6 sigma)
#define K3_CHUNK 8192                        // edges per partition block
#define K3_BLOCKS ((N_EDGES + K3_CHUNK - 1) / K3_CHUNK)   // 391
#define NT 8                                 // src tiles (tile = src>>14, 7 used)
#define GBLK 1024                            // gather blocks (all co-resident)
#define NPB 98                               // nodes per gather block

typedef unsigned short ushort_t;
typedef unsigned long long u64_t;

// ---------------- bf16 helpers ----------------
__device__ __forceinline__ float bflo(unsigned u) { return __uint_as_float(u << 16); }
__device__ __forceinline__ float bfhi(unsigned u) { return __uint_as_float(u & 0xffff0000u); }
__device__ __forceinline__ unsigned packbf(float a, float b) {
    unsigned ua = __float_as_uint(a); ua += 0x7fffu + ((ua >> 16) & 1u);
    unsigned ub = __float_as_uint(b); ub += 0x7fffu + ((ub >> 16) & 1u);
    return (ua >> 16) | (ub & 0xffff0000u);
}

// ---------------------------------------------------------------------------
// K1: partition edges into fixed-capacity bucket regions; counts -> gcursor.
// Round-7 proven shape: 256 thr, single LDS copy, long contiguous runs.
// Payload: u = src | local_dst<<17   (src < 2^17, local_dst < 512)
// ---------------------------------------------------------------------------
__global__ void partition_kernel(const int* __restrict__ src, const int* __restrict__ dst,
                                 int* __restrict__ gcursor, int* __restrict__ gsw) {
    __shared__ int h[NB], lbase[NB], lcur[NB];
    int t = threadIdx.x;
    for (int i = t; i < NB; i += 256) { h[i] = 0; lcur[i] = 0; }
    __syncthreads();
    const int4* d4 = (const int4*)dst;
    const int4* s4 = (const int4*)src;
    int i0 = blockIdx.x * (K3_CHUNK / 4) + t;
#pragma unroll
    for (int j = 0; j < K3_CHUNK / 1024; ++j) {
        int i4 = i0 + j * 256;
        if (i4 < N_EDGES / 4) {
            int4 d = d4[i4];
            atomicAdd(&h[d.x >> 9], 1);
            atomicAdd(&h[d.y >> 9], 1);
            atomicAdd(&h[d.z >> 9], 1);
            atomicAdd(&h[d.w >> 9], 1);
        }
    }
    __syncthreads();
    for (int i = t; i < NB; i += 256)
        lbase[i] = h[i] ? atomicAdd(&gcursor[i], h[i]) : 0;
    __syncthreads();
#pragma unroll
    for (int j = 0; j < K3_CHUNK / 1024; ++j) {
        int i4 = i0 + j * 256;
        if (i4 < N_EDGES / 4) {
            int4 d = d4[i4];
            int4 s = s4[i4];
            int b, r, idx;
            b = d.x >> 9; r = atomicAdd(&lcur[b], 1); idx = lbase[b] + r;
            if (idx < CAP) gsw[(size_t)b * CAP + idx] = s.x | ((d.x & (BW - 1)) << 17);
            b = d.y >> 9; r = atomicAdd(&lcur[b], 1); idx = lbase[b] + r;
            if (idx < CAP) gsw[(size_t)b * CAP + idx] = s.y | ((d.y & (BW - 1)) << 17);
            b = d.z >> 9; r = atomicAdd(&lcur[b], 1); idx = lbase[b] + r;
            if (idx < CAP) gsw[(size_t)b * CAP + idx] = s.z | ((d.z & (BW - 1)) << 17);
            b = d.w >> 9; r = atomicAdd(&lcur[b], 1); idx = lbase[b] + r;
            if (idx < CAP) gsw[(size_t)b * CAP + idx] = s.w | ((d.w & (BW - 1)) << 17);
        }
    }
}

// ---------------------------------------------------------------------------
// K2: exclusive scan of 196 bucket counts -> gbase (compact esw bases)
// ---------------------------------------------------------------------------
__global__ void scan_buckets_kernel(const int* __restrict__ gcursor, int* __restrict__ gbase,
                                    int* __restrict__ rowptr) {
    __shared__ int sa[256], sb[256];
    int t = threadIdx.x;
    int v = (t < NB) ? gcursor[t] : 0;
    sa[t] = v;
    __syncthreads();
    int* pa = sa; int* pb = sb;
    for (int off = 1; off < 256; off <<= 1) {
        int add = (t >= off) ? pa[t - off] : 0;
        pb[t] = pa[t] + add;
        __syncthreads();
        int* tmp = pa; pa = pb; pb = tmp;
    }
    int excl = pa[t] - v;
    if (t <= NB) gbase[t] = (t == NB) ? N_EDGES : excl;
    if (t == 0) rowptr[N_NODES] = N_EDGES;
}

// ---------------------------------------------------------------------------
// K3: per-bucket CSR placement, edges sorted by (dst, src-tile).
// Outputs rowptr, dinv, esw (src only), pre8 (8 x u8 tile prefix per node).
// ---------------------------------------------------------------------------
__global__ __launch_bounds__(512) void bucket_place_kernel(
        const int* __restrict__ gsw, const int* __restrict__ gcursor,
        const int* __restrict__ gbase,
        int* __restrict__ rowptr, float* __restrict__ dinv, int* __restrict__ esw,
        u64_t* __restrict__ pre8) {
    __shared__ int cntT[BW][NT];    // 16 KB: per (dst, tile) counts -> later tile prefixes
    __shared__ int curT[BW][NT];    // 16 KB: placement cursors
    __shared__ int exc[BW];
    __shared__ int sa[BW], sb[BW];
    int t = threadIdx.x;
    int k = blockIdx.x;
    int d0 = k * BW;
    for (int i = t; i < BW * NT; i += 512) { ((int*)cntT)[i] = 0; ((int*)curT)[i] = 0; }
    __syncthreads();
    int total = gcursor[k];
    const int* reg = gsw + (size_t)k * CAP;
    for (int i = t; i < total; i += 512) {
        int u = reg[i];
        atomicAdd(&cntT[u >> 17][(u & 0x1FFFF) >> 14], 1);
    }
    __syncthreads();
    // per-dst degree + tile prefix (thread t owns dst d0+t)
    int pr[NT];
    int deg = 0;
#pragma unroll
    for (int tt = 0; tt < NT; ++tt) { pr[tt] = deg; deg += cntT[t][tt]; }
    sa[t] = deg;
    __syncthreads();
    int* pa = sa; int* pb = sb;
    for (int off = 1; off < BW; off <<= 1) {
        int add = (t >= off) ? pa[t - off] : 0;
        pb[t] = pa[t] + add;
        __syncthreads();
        int* tmp = pa; pa = pb; pb = tmp;
    }
    int e_x = pa[t] - deg;
    exc[t] = e_x;
    int cbase = gbase[k];
    int d = d0 + t;
    if (d < N_NODES) {
        rowptr[d] = cbase + e_x;
        dinv[d] = rsqrtf((float)deg + 1.0f);
        u64_t pp = 0;
#pragma unroll
        for (int tt = 0; tt < NT; ++tt) pp |= (u64_t)(unsigned)pr[tt] << (8 * tt);
        pre8[d] = pp;
    }
    // overwrite own row with prefixes for the placement pass
#pragma unroll
    for (int tt = 0; tt < NT; ++tt) cntT[t][tt] = pr[tt];
    __syncthreads();
    for (int i = t; i < total; i += 512) {
        int u = reg[i];
        int ld = u >> 17;
        int sv = u & 0x1FFFF;
        int tile = sv >> 14;
        int r = atomicAdd(&curT[ld][tile], 1);
        esw[cbase + exc[ld] + cntT[ld][tile] + r] = sv;
    }
}

// ---------------------------------------------------------------------------
// Hs = (X @ W) * dinv, output bf16 row-major [N][64]. 16 nodes/block.
// ---------------------------------------------------------------------------
template <int K, bool BF16IN>
__global__ void dense_xw_kernel(const void* __restrict__ Xv, const float* __restrict__ W,
                                const float* __restrict__ dinv, ushort_t* __restrict__ Hs) {
    __shared__ float Wl[K * HID];
    __shared__ float Xl[16 * K];
    int t = threadIdx.x;
    int node0 = blockIdx.x * 16;
    for (int i = t; i < K * HID; i += 256) Wl[i] = W[i];
    if (BF16IN) {
        const uint2* X8 = (const uint2*)Xv;
        int nl = t >> 4, ci = t & 15;
        uint2 v = X8[(size_t)(node0 + nl) * 16 + ci];
        Xl[nl * K + ci * 4 + 0] = bflo(v.x);
        Xl[nl * K + ci * 4 + 1] = bfhi(v.x);
        Xl[nl * K + ci * 4 + 2] = bflo(v.y);
        Xl[nl * K + ci * 4 + 3] = bfhi(v.y);
    } else {
        const float4* X4 = (const float4*)Xv;
        for (int i = t; i < 16 * K / 4; i += 256)
            ((float4*)Xl)[i] = X4[node0 * K / 4 + i];
    }
    __syncthreads();
    int nl = t >> 4;
    int c16 = t & 15;
    int node = node0 + nl;
    float s0 = 0.f, s1 = 0.f, s2 = 0.f, s3 = 0.f;
    const float4* Wl4 = (const float4*)Wl;
#pragma unroll
    for (int k = 0; k < K; ++k) {
        float xv = Xl[nl * K + k];
        float4 w = Wl4[k * 16 + c16];
        s0 += xv * w.x; s1 += xv * w.y; s2 += xv * w.z; s3 += xv * w.w;
    }
    float di = dinv[node];
    u64_t o = ((u64_t)packbf(s2 * di, s3 * di) << 32) | packbf(s0 * di, s1 * di);
    *(u64_t*)(Hs + (size_t)node * HID + c16 * 4) = o;
}

// ---------------------------------------------------------------------------
// Src-tiled gather. 1024 co-resident blocks, each owns 98 nodes + LDS f32 acc.
// Phase loop OUTERMOST: all blocks sweep src-tile p together -> working set
// ~2.1 MB (L2-resident per XCD). Per (node,phase): 4 groups x 16 lanes x 8B.
//   r = relu( dinv[n]*(sum_e Hs[src_e] + Hs[n]) + b )
// ---------------------------------------------------------------------------
template <bool FUSE_CLS>
__global__ __launch_bounds__(256) void gather_tiled_kernel(
        const int* __restrict__ esw, const int* __restrict__ rowptr,
        const u64_t* __restrict__ pre8, const float* __restrict__ dinv,
        const ushort_t* __restrict__ Hs, const float* __restrict__ b,
        const float* __restrict__ Wc, const float* __restrict__ bc,
        void* __restrict__ Outv) {
    __shared__ float acc[NPB][HID];
    int t = threadIdx.x;
    int w = t >> 6, lane = t & 63, g = lane >> 4, s = lane & 15;
    int nbase = blockIdx.x * NPB;
    for (int i = t; i < NPB * HID; i += 256) ((float*)acc)[i] = 0.f;
    __syncthreads();
    const uint2* H8 = (const uint2*)Hs;
    for (int p = 0; p < 7; ++p) {          // tile 7 is empty (src < 2^17 range)
        for (int ln = w; ln < NPB; ln += 4) {
            int node = nbase + ln;
            if (node >= N_NODES) break;
            int beg = rowptr[node];
            u64_t pr = pre8[node];
            int o0 = (int)((pr >> (8 * p)) & 0xff);
            int o1 = (p < 6) ? (int)((pr >> (8 * p + 8)) & 0xff)
                             : (rowptr[node + 1] - beg);
            float4 a = make_float4(0.f, 0.f, 0.f, 0.f);
            for (int i = beg + o0 + g; i < beg + o1; i += 4) {
                int sv = esw[i];
                uint2 v = H8[(size_t)sv * 16 + s];
                a.x += bflo(v.x); a.y += bfhi(v.x);
                a.z += bflo(v.y); a.w += bfhi(v.y);
            }
            a.x += __shfl_xor(a.x, 16, 64); a.y += __shfl_xor(a.y, 16, 64);
            a.z += __shfl_xor(a.z, 16, 64); a.w += __shfl_xor(a.w, 16, 64);
            a.x += __shfl_xor(a.x, 32, 64); a.y += __shfl_xor(a.y, 32, 64);
            a.z += __shfl_xor(a.z, 32, 64); a.w += __shfl_xor(a.w, 32, 64);
            if (g == 0) {
                float4* ap = (float4*)&acc[ln][s * 4];
                float4 c = *ap;
                c.x += a.x; c.y += a.y; c.z += a.z; c.w += a.w;
                *ap = c;
            }
        }
    }
    // finalize: group g handles every 4th owned node of its wave (no sync needed)
    for (int k = g;; k += 4) {
        int ln = w + 4 * k;
        if (ln >= NPB) break;
        int node = nbase + ln;
        if (node >= N_NODES) break;
        float4 av = *(float4*)&acc[ln][s * 4];
        uint2 hn = H8[(size_t)node * 16 + s];
        float di = dinv[node];
        float4 bb = ((const float4*)b)[s];
        float rx = fmaxf(di * (av.x + bflo(hn.x)) + bb.x, 0.f);
        float ry = fmaxf(di * (av.y + bfhi(hn.x)) + bb.y, 0.f);
        float rz = fmaxf(di * (av.z + bflo(hn.y)) + bb.z, 0.f);
        float rw = fmaxf(di * (av.w + bfhi(hn.y)) + bb.w, 0.f);
        if (!FUSE_CLS) {
            u64_t o = ((u64_t)packbf(rz, rw) << 32) | packbf(rx, ry);
            *(u64_t*)((ushort_t*)Outv + (size_t)node * HID + s * 4) = o;
        } else {
            float4 wc = ((const float4*)Wc)[s];
            float v = rx * wc.x + ry * wc.y + rz * wc.z + rw * wc.w;
            v += __shfl_xor(v, 1, 64);
            v += __shfl_xor(v, 2, 64);
            v += __shfl_xor(v, 4, 64);
            v += __shfl_xor(v, 8, 64);
            if (s == 0) ((float*)Outv)[node] = 1.0f / (1.0f + expf(-(v + bc[0])));
        }
    }
}

// ---------------------------------------------------------------------------
extern "C" void kernel_launch(void* const* d_in, const int* in_sizes, int n_in,
                              void* d_out, int out_size, void* d_ws, size_t ws_size,
                              hipStream_t stream) {
    const float* x  = (const float*)d_in[0];
    const int* ei   = (const int*)d_in[1];
    const float* W1 = (const float*)d_in[2];
    const float* b1 = (const float*)d_in[3];
    const float* W2 = (const float*)d_in[4];
    const float* b2 = (const float*)d_in[5];
    const float* Wc = (const float*)d_in[6];
    const float* bc = (const float*)d_in[7];
    float* out = (float*)d_out;

    const int* src = ei;
    const int* dst = ei + N_EDGES;

    // Workspace: gsw[NB*CAP] | esw[E] | rowptr[N+8] | dinv[N] | gcursor[512] |
    //            gbase[512] | pre8[N] u64 | A[N*64] bf16 | B[N*64] bf16
    int*   gsw    = (int*)d_ws;
    int*   esw    = gsw + (size_t)NB * CAP;
    int*   rowptr = esw + N_EDGES;
    float* dinv   = (float*)(rowptr + N_NODES + 8);
    int*   gcursor= (int*)(dinv + N_NODES);
    int*   gbase  = gcursor + 512;
    u64_t* pre8   = (u64_t*)(gbase + 512);
    ushort_t* A   = (ushort_t*)(pre8 + N_NODES);
    ushort_t* B   = A + (size_t)N_NODES * HID;

    int node16 = N_NODES / 16;   // 6250

    // ---- CSR build (fixed-capacity bucket sort, src-tile sorted) ----
    hipMemsetAsync(gcursor, 0, NB * sizeof(int), stream);
    partition_kernel<<<K3_BLOCKS, 256, 0, stream>>>(src, dst, gcursor, gsw);
    scan_buckets_kernel<<<1, 256, 0, stream>>>(gcursor, gbase, rowptr);
    bucket_place_kernel<<<NB, 512, 0, stream>>>(gsw, gcursor, gbase, rowptr, dinv, esw, pre8);

    // ---- layer 1 ----
    dense_xw_kernel<IN_CH, false><<<node16, 256, 0, stream>>>(x, W1, dinv, A);
    gather_tiled_kernel<false><<<GBLK, 256, 0, stream>>>(esw, rowptr, pre8, dinv, A, b1,
                                                         nullptr, nullptr, B);

    // ---- layer 2 + fused classifier ----
    dense_xw_kernel<HID, true><<<node16, 256, 0, stream>>>(B, W2, dinv, A);
    gather_tiled_kernel<true><<<GBLK, 256, 0, stream>>>(esw, rowptr, pre8, dinv, A, b2,
                                                        Wc, bc, out);
}

// Round 10
// 249.797 us; speedup vs baseline: 2.2987x; 2.2987x over previous
//
#include <hip/hip_runtime.h>
#include <math.h>

#define N_NODES 100000
#define N_EDGES 3200000
#define IN_CH 32
#define HID 64
#define BW 512                               // dst nodes per bucket
#define NB ((N_NODES + BW - 1) / BW)         // 196 buckets
#define CAP 17408                            // fixed capacity (mean 16384 + >6 sigma)
#define K3_CHUNK 8192                        // edges per partition block
#define K3_BLOCKS ((N_EDGES + K3_CHUNK - 1) / K3_CHUNK)   // 391

typedef unsigned short ushort_t;
typedef unsigned long long u64_t;

// ---------------- bf16 helpers ----------------
__device__ __forceinline__ float bflo(unsigned u) { return __uint_as_float(u << 16); }
__device__ __forceinline__ float bfhi(unsigned u) { return __uint_as_float(u & 0xffff0000u); }
__device__ __forceinline__ unsigned packbf(float a, float b) {
    unsigned ua = __float_as_uint(a); ua += 0x7fffu + ((ua >> 16) & 1u);
    unsigned ub = __float_as_uint(b); ub += 0x7fffu + ((ub >> 16) & 1u);
    return (ua >> 16) | (ub & 0xffff0000u);
}

// ---------------------------------------------------------------------------
// K1: partition edges into fixed-capacity bucket regions; counts -> gcursor.
// Payload: u = src | local_dst<<17   (src < 2^17, local_dst < 512)
// ---------------------------------------------------------------------------
__global__ void partition_kernel(const int* __restrict__ src, const int* __restrict__ dst,
                                 int* __restrict__ gcursor, int* __restrict__ gsw) {
    __shared__ int h[NB], lbase[NB], lcur[NB];
    int t = threadIdx.x;
    for (int i = t; i < NB; i += 256) { h[i] = 0; lcur[i] = 0; }
    __syncthreads();
    const int4* d4 = (const int4*)dst;
    const int4* s4 = (const int4*)src;
    int i0 = blockIdx.x * (K3_CHUNK / 4) + t;
#pragma unroll
    for (int j = 0; j < K3_CHUNK / 1024; ++j) {
        int i4 = i0 + j * 256;
        if (i4 < N_EDGES / 4) {
            int4 d = d4[i4];
            atomicAdd(&h[d.x >> 9], 1);
            atomicAdd(&h[d.y >> 9], 1);
            atomicAdd(&h[d.z >> 9], 1);
            atomicAdd(&h[d.w >> 9], 1);
        }
    }
    __syncthreads();
    for (int i = t; i < NB; i += 256)
        lbase[i] = h[i] ? atomicAdd(&gcursor[i], h[i]) : 0;
    __syncthreads();
#pragma unroll
    for (int j = 0; j < K3_CHUNK / 1024; ++j) {
        int i4 = i0 + j * 256;
        if (i4 < N_EDGES / 4) {
            int4 d = d4[i4];
            int4 s = s4[i4];
            int b, r, idx;
            b = d.x >> 9; r = atomicAdd(&lcur[b], 1); idx = lbase[b] + r;
            if (idx < CAP) gsw[(size_t)b * CAP + idx] = s.x | ((d.x & (BW - 1)) << 17);
            b = d.y >> 9; r = atomicAdd(&lcur[b], 1); idx = lbase[b] + r;
            if (idx < CAP) gsw[(size_t)b * CAP + idx] = s.y | ((d.y & (BW - 1)) << 17);
            b = d.z >> 9; r = atomicAdd(&lcur[b], 1); idx = lbase[b] + r;
            if (idx < CAP) gsw[(size_t)b * CAP + idx] = s.z | ((d.z & (BW - 1)) << 17);
            b = d.w >> 9; r = atomicAdd(&lcur[b], 1); idx = lbase[b] + r;
            if (idx < CAP) gsw[(size_t)b * CAP + idx] = s.w | ((d.w & (BW - 1)) << 17);
        }
    }
}

// ---------------------------------------------------------------------------
// K2: exclusive scan of 196 bucket counts -> gbase (compact esw bases)
// ---------------------------------------------------------------------------
__global__ void scan_buckets_kernel(const int* __restrict__ gcursor, int* __restrict__ gbase,
                                    int* __restrict__ rowptr) {
    __shared__ int sa[256], sb[256];
    int t = threadIdx.x;
    int v = (t < NB) ? gcursor[t] : 0;
    sa[t] = v;
    __syncthreads();
    int* pa = sa; int* pb = sb;
    for (int off = 1; off < 256; off <<= 1) {
        int add = (t >= off) ? pa[t - off] : 0;
        pb[t] = pa[t] + add;
        __syncthreads();
        int* tmp = pa; pa = pb; pb = tmp;
    }
    int excl = pa[t] - v;
    if (t <= NB) gbase[t] = (t == NB) ? N_EDGES : excl;
    if (t == 0) rowptr[N_NODES] = N_EDGES;
}

// ---------------------------------------------------------------------------
// K3: per-bucket exact CSR placement (rowptr, dinv, compact esw=src).
// ---------------------------------------------------------------------------
__global__ __launch_bounds__(512) void bucket_place_kernel(
        const int* __restrict__ gsw, const int* __restrict__ gcursor,
        const int* __restrict__ gbase,
        int* __restrict__ rowptr, float* __restrict__ dinv, int* __restrict__ esw) {
    __shared__ int cnt[BW], exc[BW], cur[BW];
    __shared__ int sa[BW], sb[BW];
    int t = threadIdx.x;
    int k = blockIdx.x;
    int d0 = k * BW;
    cnt[t] = 0; cur[t] = 0;
    __syncthreads();
    int total = gcursor[k];
    if (total > CAP) total = CAP;
    const int* reg = gsw + (size_t)k * CAP;
    for (int i = t; i < total; i += 512)
        atomicAdd(&cnt[reg[i] >> 17], 1);
    __syncthreads();
    sa[t] = cnt[t];
    __syncthreads();
    int* pa = sa; int* pb = sb;
    for (int off = 1; off < BW; off <<= 1) {
        int add = (t >= off) ? pa[t - off] : 0;
        pb[t] = pa[t] + add;
        __syncthreads();
        int* tmp = pa; pa = pb; pb = tmp;
    }
    int e_x = pa[t] - cnt[t];
    exc[t] = e_x;
    int cbase = gbase[k];
    int d = d0 + t;
    if (d < N_NODES) {
        rowptr[d] = cbase + e_x;
        dinv[d] = rsqrtf((float)cnt[t] + 1.0f);
    }
    __syncthreads();
    for (int i = t; i < total; i += 512) {
        int u = reg[i];
        int ld = u >> 17;
        int r = atomicAdd(&cur[ld], 1);
        esw[cbase + exc[ld] + r] = u & 0x1FFFF;
    }
}

// ---------------------------------------------------------------------------
// K4: Xs = X * dinv[node], f32 [N][32] -> bf16 [N][32]. Thread = 4 channels.
// ---------------------------------------------------------------------------
__global__ void xs_kernel(const float* __restrict__ X, const float* __restrict__ dinv,
                          ushort_t* __restrict__ Xs) {
    int i = blockIdx.x * blockDim.x + threadIdx.x;   // uint2 index, N*8 total
    if (i >= N_NODES * 8) return;
    int node = i >> 3;
    float di = dinv[node];
    const float4* X4 = (const float4*)X;
    float4 v = X4[i];
    u64_t o = ((u64_t)packbf(v.z * di, v.w * di) << 32) | packbf(v.x * di, v.y * di);
    *(u64_t*)((uint2*)Xs + i) = o;
}

// ---------------------------------------------------------------------------
// K5: layer-1 gather over 64B bf16 Xs rows.
//   y[d] = dinv[d] * (sum_e Xs[src_e] + Xs[d])    (f32 [N][32])
// Wave per node: 8 edge-groups x 8 lanes x uint2.
// ---------------------------------------------------------------------------
__global__ void gather_x_kernel(const int* __restrict__ esw, const int* __restrict__ rowptr,
                                const float* __restrict__ dinv, const ushort_t* __restrict__ Xs,
                                float* __restrict__ y) {
    int t = threadIdx.x;
    int node = blockIdx.x * 4 + (t >> 6);
    int lane = t & 63;
    int g = lane >> 3, s = lane & 7;
    int beg = rowptr[node], end = rowptr[node + 1];
    const uint2* H8 = (const uint2*)Xs;     // row stride 8 (32 ch)
    float4 acc = make_float4(0.f, 0.f, 0.f, 0.f);
    int i = beg + g;
    for (; i + 8 < end; i += 16) {
        int s0 = esw[i];
        int s1 = esw[i + 8];
        uint2 v0 = H8[(size_t)s0 * 8 + s];
        uint2 v1 = H8[(size_t)s1 * 8 + s];
        acc.x += bflo(v0.x) + bflo(v1.x);
        acc.y += bfhi(v0.x) + bfhi(v1.x);
        acc.z += bflo(v0.y) + bflo(v1.y);
        acc.w += bfhi(v0.y) + bfhi(v1.y);
    }
    if (i < end) {
        int s0 = esw[i];
        uint2 v0 = H8[(size_t)s0 * 8 + s];
        acc.x += bflo(v0.x);
        acc.y += bfhi(v0.x);
        acc.z += bflo(v0.y);
        acc.w += bfhi(v0.y);
    }
    // reduce across the 8 edge-groups (lane bits 3..5)
    acc.x += __shfl_xor(acc.x, 8, 64);  acc.y += __shfl_xor(acc.y, 8, 64);
    acc.z += __shfl_xor(acc.z, 8, 64);  acc.w += __shfl_xor(acc.w, 8, 64);
    acc.x += __shfl_xor(acc.x, 16, 64); acc.y += __shfl_xor(acc.y, 16, 64);
    acc.z += __shfl_xor(acc.z, 16, 64); acc.w += __shfl_xor(acc.w, 16, 64);
    acc.x += __shfl_xor(acc.x, 32, 64); acc.y += __shfl_xor(acc.y, 32, 64);
    acc.z += __shfl_xor(acc.z, 32, 64); acc.w += __shfl_xor(acc.w, 32, 64);

    if (g == 0) {
        uint2 hn = H8[(size_t)node * 8 + s];
        float di = dinv[node];
        float4 r;
        r.x = di * (acc.x + bflo(hn.x));
        r.y = di * (acc.y + bfhi(hn.x));
        r.z = di * (acc.z + bflo(hn.y));
        r.w = di * (acc.w + bfhi(hn.y));
        ((float4*)y)[(size_t)node * 8 + s] = r;
    }
}

// ---------------------------------------------------------------------------
// K6: fused dense: H1 = relu(y@W1 + b1); Hs2 = (H1@W2)*dinv -> bf16 [N][64]
// Block = 16 nodes x 256 thr. W1(8KB) + W2(16KB) + y(2KB) + H1(4KB) in LDS.
// ---------------------------------------------------------------------------
__global__ void dense12_kernel(const float* __restrict__ y, const float* __restrict__ W1,
                               const float* __restrict__ b1, const float* __restrict__ W2,
                               const float* __restrict__ dinv, ushort_t* __restrict__ Hs2) {
    __shared__ float W1l[IN_CH * HID];
    __shared__ float W2l[HID * HID];
    __shared__ float Yl[16 * IN_CH];
    __shared__ float H1l[16 * HID];
    int t = threadIdx.x;
    int node0 = blockIdx.x * 16;
    for (int i = t; i < IN_CH * HID; i += 256) W1l[i] = W1[i];
    for (int i = t; i < HID * HID; i += 256) W2l[i] = W2[i];
    for (int i = t; i < 16 * IN_CH; i += 256) Yl[i] = y[(size_t)node0 * IN_CH + i];
    __syncthreads();
    int nl = t >> 4;       // node 0..15
    int c16 = t & 15;      // channel group: ch0 = c16*4
    // phase A: H1 = relu(y @ W1 + b1)
    float4 bb = ((const float4*)b1)[c16];
    float s0 = bb.x, s1 = bb.y, s2 = bb.z, s3 = bb.w;
    const float4* W14 = (const float4*)W1l;
#pragma unroll
    for (int k = 0; k < IN_CH; ++k) {
        float xv = Yl[nl * IN_CH + k];
        float4 w = W14[k * 16 + c16];
        s0 += xv * w.x; s1 += xv * w.y; s2 += xv * w.z; s3 += xv * w.w;
    }
    H1l[nl * HID + c16 * 4 + 0] = fmaxf(s0, 0.f);
    H1l[nl * HID + c16 * 4 + 1] = fmaxf(s1, 0.f);
    H1l[nl * HID + c16 * 4 + 2] = fmaxf(s2, 0.f);
    H1l[nl * HID + c16 * 4 + 3] = fmaxf(s3, 0.f);
    __syncthreads();
    // phase B: Hs2 = (H1 @ W2) * dinv
    float r0 = 0.f, r1 = 0.f, r2 = 0.f, r3 = 0.f;
    const float4* W24 = (const float4*)W2l;
#pragma unroll
    for (int k = 0; k < HID; ++k) {
        float hv = H1l[nl * HID + k];
        float4 w = W24[k * 16 + c16];
        r0 += hv * w.x; r1 += hv * w.y; r2 += hv * w.z; r3 += hv * w.w;
    }
    int node = node0 + nl;
    float di = dinv[node];
    u64_t o = ((u64_t)packbf(r2 * di, r3 * di) << 32) | packbf(r0 * di, r1 * di);
    *(u64_t*)(Hs2 + (size_t)node * HID + c16 * 4) = o;
}

// ---------------------------------------------------------------------------
// K7: layer-2 gather over 128B bf16 Hs2 rows + fused classifier.
//   r = relu( dinv[n]*(sum_e Hs2[src_e] + Hs2[n]) + b2 )
//   out[n] = sigmoid(dot(r, Wc) + bc)
// Wave per node: 4 edge-groups x 16 lanes x uint2 (round-4 proven form).
// ---------------------------------------------------------------------------
__global__ void gather_cls_kernel(const int* __restrict__ esw, const int* __restrict__ rowptr,
                                  const float* __restrict__ dinv, const ushort_t* __restrict__ Hs,
                                  const float* __restrict__ b,
                                  const float* __restrict__ Wc, const float* __restrict__ bc,
                                  float* __restrict__ out) {
    int t = threadIdx.x;
    int node = blockIdx.x * 4 + (t >> 6);
    int lane = t & 63;
    int g = lane >> 4, s = lane & 15;
    int beg = rowptr[node], end = rowptr[node + 1];
    int cnt = end - beg;
    const uint2* H8 = (const uint2*)Hs;
    float4 acc = make_float4(0.f, 0.f, 0.f, 0.f);
    int i = g;
    for (; i + 12 < cnt; i += 16) {
        int s0 = esw[beg + i];
        int s1 = esw[beg + i + 4];
        int s2 = esw[beg + i + 8];
        int s3 = esw[beg + i + 12];
        uint2 v0 = H8[(size_t)s0 * 16 + s];
        uint2 v1 = H8[(size_t)s1 * 16 + s];
        uint2 v2 = H8[(size_t)s2 * 16 + s];
        uint2 v3 = H8[(size_t)s3 * 16 + s];
        acc.x += (bflo(v0.x) + bflo(v1.x)) + (bflo(v2.x) + bflo(v3.x));
        acc.y += (bfhi(v0.x) + bfhi(v1.x)) + (bfhi(v2.x) + bfhi(v3.x));
        acc.z += (bflo(v0.y) + bflo(v1.y)) + (bflo(v2.y) + bflo(v3.y));
        acc.w += (bfhi(v0.y) + bfhi(v1.y)) + (bfhi(v2.y) + bfhi(v3.y));
    }
    for (; i < cnt; i += 4) {
        int s0 = esw[beg + i];
        uint2 v0 = H8[(size_t)s0 * 16 + s];
        acc.x += bflo(v0.x);
        acc.y += bfhi(v0.x);
        acc.z += bflo(v0.y);
        acc.w += bfhi(v0.y);
    }
    acc.x += __shfl_xor(acc.x, 16, 64); acc.y += __shfl_xor(acc.y, 16, 64);
    acc.z += __shfl_xor(acc.z, 16, 64); acc.w += __shfl_xor(acc.w, 16, 64);
    acc.x += __shfl_xor(acc.x, 32, 64); acc.y += __shfl_xor(acc.y, 32, 64);
    acc.z += __shfl_xor(acc.z, 32, 64); acc.w += __shfl_xor(acc.w, 32, 64);

    uint2 hn = H8[(size_t)node * 16 + s];
    float di = dinv[node];
    float4 bb = ((const float4*)b)[s];
    float rx = fmaxf(di * (acc.x + bflo(hn.x)) + bb.x, 0.f);
    float ry = fmaxf(di * (acc.y + bfhi(hn.x)) + bb.y, 0.f);
    float rz = fmaxf(di * (acc.z + bflo(hn.y)) + bb.z, 0.f);
    float rw = fmaxf(di * (acc.w + bfhi(hn.y)) + bb.w, 0.f);

    float4 wc = ((const float4*)Wc)[s];
    float v = rx * wc.x + ry * wc.y + rz * wc.z + rw * wc.w;
#pragma unroll
    for (int off = 1; off < 16; off <<= 1) v += __shfl_xor(v, off, 64);
    if (lane == 0) out[node] = 1.0f / (1.0f + expf(-(v + bc[0])));
}

// ---------------------------------------------------------------------------
extern "C" void kernel_launch(void* const* d_in, const int* in_sizes, int n_in,
                              void* d_out, int out_size, void* d_ws, size_t ws_size,
                              hipStream_t stream) {
    const float* x  = (const float*)d_in[0];
    const int* ei   = (const int*)d_in[1];
    const float* W1 = (const float*)d_in[2];
    const float* b1 = (const float*)d_in[3];
    const float* W2 = (const float*)d_in[4];
    const float* b2 = (const float*)d_in[5];
    const float* Wc = (const float*)d_in[6];
    const float* bc = (const float*)d_in[7];
    float* out = (float*)d_out;

    const int* src = ei;
    const int* dst = ei + N_EDGES;

    // Workspace: gsw[NB*CAP] | esw[E] | rowptr[N+8] | dinv[N] | gcursor[512] |
    //            gbase[512] | Xs[N*32] bf16 | y[N*32] f32 | Hs2[N*64] bf16
    int*   gsw    = (int*)d_ws;
    int*   esw    = gsw + (size_t)NB * CAP;
    int*   rowptr = esw + N_EDGES;
    float* dinv   = (float*)(rowptr + N_NODES + 8);
    int*   gcursor= (int*)(dinv + N_NODES);
    int*   gbase  = gcursor + 512;
    ushort_t* Xs  = (ushort_t*)(gbase + 512);
    float*    y   = (float*)(Xs + (size_t)N_NODES * IN_CH);
    ushort_t* Hs2 = (ushort_t*)(y + (size_t)N_NODES * IN_CH);

    int node16 = N_NODES / 16;   // 6250
    int node4  = N_NODES / 4;    // 25000

    // ---- CSR build (fixed-capacity bucket sort) ----
    hipMemsetAsync(gcursor, 0, NB * sizeof(int), stream);
    partition_kernel<<<K3_BLOCKS, 256, 0, stream>>>(src, dst, gcursor, gsw);
    scan_buckets_kernel<<<1, 256, 0, stream>>>(gcursor, gbase, rowptr);
    bucket_place_kernel<<<NB, 512, 0, stream>>>(gsw, gcursor, gbase, rowptr, dinv, esw);

    // ---- layer 1: gather raw X (64B rows), then fused dense W1+relu+W2 ----
    xs_kernel<<<(N_NODES * 8 + 255) / 256, 256, 0, stream>>>(x, dinv, Xs);
    gather_x_kernel<<<node4, 256, 0, stream>>>(esw, rowptr, dinv, Xs, y);
    dense12_kernel<<<node16, 256, 0, stream>>>(y, W1, b1, W2, dinv, Hs2);

    // ---- layer 2 gather + fused classifier ----
    gather_cls_kernel<<<node4, 256, 0, stream>>>(esw, rowptr, dinv, Hs2, b2, Wc, bc, out);
}